// Round 1
// baseline (10340.384 us; speedup 1.0000x reference)
//
#include <hip/hip_runtime.h>
#include <hip/hip_bf16.h>

// Problem constants
#define BB_ 2
#define SS_ 1024
#define FIN_ 64
#define EE_ 256
#define FF_ 1024
#define WW_ 64
#define NH_ 8
#define HD_ 32
#define OUT_ 10
#define NWIN (BB_ * SS_)
#define NT 512
#define SCALE_ 0.17677669529663687f  // 1/sqrt(32)

__device__ __forceinline__ float dot4(float4 a, float4 b) {
    return a.x * b.x + a.y * b.y + a.z * b.z + a.w * b.w;
}

__device__ __forceinline__ float wsum(float v) {
#pragma unroll
    for (int o = 32; o > 0; o >>= 1) v += __shfl_xor(v, o, 64);
    return v;
}

__device__ __forceinline__ float wmax(float v) {
#pragma unroll
    for (int o = 32; o > 0; o >>= 1) v = fmaxf(v, __shfl_xor(v, o, 64));
    return v;
}

__device__ __forceinline__ float silu_f(float h) {
    return h / (1.f + __expf(-h));
}

// ---------------------------------------------------------------------------
// Kernel 1: emb[t, e] = inputs[t, :] @ embed_w[e, :] + embed_b[e]
// grid = 2048, block = 256
// ---------------------------------------------------------------------------
__global__ void k_embed(const float* __restrict__ in, const float* __restrict__ w,
                        const float* __restrict__ bias, float* __restrict__ emb) {
    __shared__ float row[FIN_];
    const int t = blockIdx.x;
    if (threadIdx.x < FIN_) row[threadIdx.x] = in[t * FIN_ + threadIdx.x];
    __syncthreads();
    const int e = threadIdx.x;
    const float4* w4 = (const float4*)(w + e * FIN_);
    const float4* r4 = (const float4*)row;
    float s = 0.f;
#pragma unroll
    for (int c = 0; c < FIN_ / 4; ++c) s += dot4(w4[c], r4[c]);
    emb[t * EE_ + e] = s + bias[e];
}

// ---------------------------------------------------------------------------
// Kernel 2: qkv_tok[t, j] = emb[t, :] @ qkv_w0[j, :] + qkv_b0[j]   (layer 0)
// grid = 2048, block = 256
// ---------------------------------------------------------------------------
__global__ void k_qkv0(const float* __restrict__ emb, const float* __restrict__ qkvw,
                       const float* __restrict__ qkvb, float* __restrict__ qkv) {
    __shared__ float row[EE_];
    const int t = blockIdx.x;
    row[threadIdx.x] = emb[t * EE_ + threadIdx.x];
    __syncthreads();
    const float4* r4 = (const float4*)row;
    for (int j = threadIdx.x; j < 3 * EE_; j += 256) {
        const float4* w4 = (const float4*)(qkvw + j * EE_);
        float s = 0.f;
#pragma unroll 8
        for (int c = 0; c < EE_ / 4; ++c) s += dot4(w4[c], r4[c]);
        qkv[t * 3 * EE_ + j] = s + qkvb[j];
    }
}

// ---------------------------------------------------------------------------
// Fused per-window kernel. One block per window (2048 blocks x 512 threads).
// LDS state: xr[64][260] fp32 window state; padded pitches for staging.
// ---------------------------------------------------------------------------
#define XP 260   // xr pitch (16B-aligned rows, banks spread via +4)
#define QP 36    // q/k/v staging pitch (144B rows: aligned, conflict-free)
#define SP 68    // scores pitch

struct SMem {
    float xr[64 * XP];   // 65,  window state (residual accumulator)
    float qs[64 * QP];   // q staging / o staging / k1 staging / ffn2 partials
    float kv[64 * QP];   // k then v staging / v1 staging
    float U[8192];       // scores (pitch 68) OR ffn hidden tile [8][1024]
    float sbuf[64];
    float q1b[32];
    float o1b[256];
    float x2b[256];
    float x3b[256];
    float stat[4];
};

__device__ __forceinline__ void ln_rows64(float* xr, const float* __restrict__ g,
                                          const float* __restrict__ b, int wv, int lane) {
    const float g0 = g[lane], g1 = g[lane + 64], g2 = g[lane + 128], g3 = g[lane + 192];
    const float b0 = b[lane], b1 = b[lane + 64], b2 = b[lane + 128], b3 = b[lane + 192];
    for (int r = 0; r < 8; ++r) {
        float* row = xr + (wv * 8 + r) * XP;
        float v0 = row[lane], v1 = row[lane + 64], v2 = row[lane + 128], v3 = row[lane + 192];
        const float m = wsum(v0 + v1 + v2 + v3) * 0.00390625f;
        const float d0 = v0 - m, d1 = v1 - m, d2 = v2 - m, d3 = v3 - m;
        const float var = wsum(d0 * d0 + d1 * d1 + d2 * d2 + d3 * d3) * 0.00390625f;
        const float rs = rsqrtf(var + 1e-5f);
        row[lane] = d0 * rs * g0 + b0;
        row[lane + 64] = d1 * rs * g1 + b1;
        row[lane + 128] = d2 * rs * g2 + b2;
        row[lane + 192] = d3 * rs * g3 + b3;
    }
}

__device__ __forceinline__ void ln_vec256(float* buf, const float* __restrict__ g,
                                          const float* __restrict__ b, float* stat, int tid) {
    if (tid < 64) {
        const float a0 = buf[tid], a1 = buf[tid + 64], a2 = buf[tid + 128], a3 = buf[tid + 192];
        const float m = wsum(a0 + a1 + a2 + a3) * 0.00390625f;
        const float d0 = a0 - m, d1 = a1 - m, d2 = a2 - m, d3 = a3 - m;
        const float var = wsum(d0 * d0 + d1 * d1 + d2 * d2 + d3 * d3) * 0.00390625f;
        if (tid == 0) { stat[0] = m; stat[1] = rsqrtf(var + 1e-5f); }
    }
    __syncthreads();
    if (tid < 256) {
        const float m = stat[0], rs = stat[1];
        buf[tid] = (buf[tid] - m) * rs * g[tid] + b[tid];
    }
    __syncthreads();
}

__global__ __launch_bounds__(NT) void k_fused(
    const float* __restrict__ emb, const float* __restrict__ qkv_tok,
    const float* __restrict__ qkv_w, const float* __restrict__ qkv_b,
    const float* __restrict__ aow, const float* __restrict__ aob,
    const float* __restrict__ ln1g, const float* __restrict__ ln1b,
    const float* __restrict__ f1w, const float* __restrict__ f1b,
    const float* __restrict__ f2w, const float* __restrict__ f2b,
    const float* __restrict__ ln2g, const float* __restrict__ ln2b,
    const float* __restrict__ hw, const float* __restrict__ hb,
    float* __restrict__ out) {
    __shared__ SMem sm;
    const int n = blockIdx.x;
    const int bb = n >> 10, p = n & 1023;
    const int tid = threadIdx.x;
    const int lane = tid & 63, wv = tid >> 6;

    // Layer-1 parameter bases
    const float* qkv_w1 = qkv_w + 3 * EE_ * EE_;
    const float* qkv_b1 = qkv_b + 3 * EE_;
    const float* aow1 = aow + EE_ * EE_;
    const float* aob1 = aob + EE_;
    const float* f1w1 = f1w + FF_ * EE_;
    const float* f1b1 = f1b + FF_;
    const float* f2w1 = f2w + EE_ * FF_;
    const float* f2b1 = f2b + EE_;

    // ---- Phase 0: init state xr = x0 (gathered emb, zeros for pad) + attn_out_b[0]
    for (int idx = tid; idx < 64 * EE_; idx += NT) {
        const int i = idx >> 8, e = idx & 255;
        const int t = p - 63 + i;
        const float v = (t >= 0) ? emb[((bb << 10) + t) * EE_ + e] : 0.f;
        sm.xr[i * XP + e] = v + aob[e];
    }

    // =================== Layer 0: attention, 8 heads ===================
    for (int h = 0; h < NH_; ++h) {
        // (a) gather q -> qs, k -> kv from qkv_tok (bias-only rows for pad)
        __syncthreads();
        for (int idx = tid; idx < 2048; idx += NT) {
            const int i = idx >> 5, d = idx & 31;
            const int t = p - 63 + i;
            const float* src = (t >= 0) ? (qkv_tok + ((bb << 10) + t) * 3 * EE_) : qkv_b;
            sm.qs[i * QP + d] = src[h * HD_ + d];
            sm.kv[i * QP + d] = src[EE_ + h * HD_ + d];
        }
        __syncthreads();
        // (b) scores: sc[i][j] = scale * q_i . k_j   (thread: 1 row i, 8 cols j)
        {
            const int i = tid >> 3;
            const int j0 = tid & 7;
            const float4* qrow = (const float4*)(sm.qs + i * QP);
            float4 q[8];
#pragma unroll
            for (int c = 0; c < 8; ++c) q[c] = qrow[c];
#pragma unroll
            for (int k = 0; k < 8; ++k) {
                const int j = j0 + 8 * k;
                const float4* krow = (const float4*)(sm.kv + j * QP);
                float s = 0.f;
#pragma unroll
                for (int c = 0; c < 8; ++c) s += dot4(q[c], krow[c]);
                sm.U[i * SP + j] = s * SCALE_;
            }
        }
        __syncthreads();
        // (c) softmax rows (wave handles 8 rows) + (d) load v over k
        for (int r = 0; r < 8; ++r) {
            const int i = wv * 8 + r;
            const float x = sm.U[i * SP + lane];
            const float m = wmax(x);
            const float ex = __expf(x - m);
            const float su = wsum(ex);
            sm.U[i * SP + lane] = ex / su;
        }
        for (int idx = tid; idx < 2048; idx += NT) {
            const int i = idx >> 5, d = idx & 31;
            const int t = p - 63 + i;
            const float* src = (t >= 0) ? (qkv_tok + ((bb << 10) + t) * 3 * EE_) : qkv_b;
            sm.kv[i * QP + d] = src[2 * EE_ + h * HD_ + d];
        }
        __syncthreads();
        // (e) o = P @ V  -> overwrite qs (q is dead)
        {
            const int i = tid >> 3;
            const int d0 = (tid & 7) * 4;
            float4 acc = {0.f, 0.f, 0.f, 0.f};
            const float* prow = sm.U + i * SP;
            for (int j = 0; j < 64; ++j) {
                const float pp = prow[j];
                const float4 v4 = *(const float4*)(sm.kv + j * QP + d0);
                acc.x += pp * v4.x; acc.y += pp * v4.y;
                acc.z += pp * v4.z; acc.w += pp * v4.w;
            }
            *(float4*)(sm.qs + i * QP + d0) = acc;
        }
        __syncthreads();
        // (f) proj fold: xr[i][e] += o_h[i][:] . Wo[e][h*32:h*32+32]
        {
            const int e = tid & 255;
            const int ih = tid >> 8;
            const float* wrow = aow + e * EE_ + h * HD_;
            float4 w[8];
#pragma unroll
            for (int d = 0; d < 8; ++d) w[d] = *(const float4*)(wrow + d * 4);
            for (int k = 0; k < 32; ++k) {
                const int i = ih * 32 + k;
                const float4* orow = (const float4*)(sm.qs + i * QP);
                float s = 0.f;
#pragma unroll
                for (int d = 0; d < 8; ++d) s += dot4(orow[d], w[d]);
                sm.xr[i * XP + e] += s;
            }
        }
    }
    __syncthreads();

    // ---- LN1 (layer 0)
    ln_rows64(sm.xr, ln1g, ln1b, wv, lane);
    __syncthreads();

    // ---- FFN (layer 0): 8 tiles of 8 tokens; hidden tile in U (fp32)
    for (int tt = 0; tt < 8; ++tt) {
        __syncthreads();  // protect U reuse across tiles
        // ffn1: thread computes f0=tid and f1=tid+512 for the tile's 8 tokens
        {
            float acc0[8], acc1[8];
#pragma unroll
            for (int i = 0; i < 8; ++i) { acc0[i] = 0.f; acc1[i] = 0.f; }
            const float* w0r = f1w + tid * EE_;
            const float* w1r = f1w + (tid + 512) * EE_;
            for (int c4 = 0; c4 < 64; ++c4) {
                const float4 wa = *(const float4*)(w0r + c4 * 4);
                const float4 wb = *(const float4*)(w1r + c4 * 4);
#pragma unroll
                for (int i = 0; i < 8; ++i) {
                    const float4 x = *(const float4*)(sm.xr + (tt * 8 + i) * XP + c4 * 4);
                    acc0[i] += dot4(x, wa);
                    acc1[i] += dot4(x, wb);
                }
            }
            const float bA = f1b[tid], bBv = f1b[tid + 512];
#pragma unroll
            for (int i = 0; i < 8; ++i) {
                sm.U[i * 1024 + tid] = silu_f(acc0[i] + bA);
                sm.U[i * 1024 + tid + 512] = silu_f(acc1[i] + bBv);
            }
        }
        __syncthreads();
        // ffn2: f-split across the two 256-thread groups, partials via qs
        {
            const int g = tid >> 8;
            const int e = tid & 255;
            const float* w2r = f2w + e * FF_ + g * 512;
            const float* hbse = sm.U + g * 512;
            float acc[8];
#pragma unroll
            for (int i = 0; i < 8; ++i) acc[i] = 0.f;
            for (int f4 = 0; f4 < 128; ++f4) {
                const float4 w = *(const float4*)(w2r + f4 * 4);
#pragma unroll
                for (int i = 0; i < 8; ++i) {
                    const float4 hh = *(const float4*)(hbse + i * 1024 + f4 * 4);
                    acc[i] += dot4(hh, w);
                }
            }
            if (g == 1) {
#pragma unroll
                for (int i = 0; i < 8; ++i) sm.qs[i * 256 + e] = acc[i];
            }
            __syncthreads();
            if (g == 0) {
                const float b2v = f2b[e];
#pragma unroll
                for (int i = 0; i < 8; ++i)
                    sm.xr[(tt * 8 + i) * XP + e] += acc[i] + sm.qs[i * 256 + e] + b2v;
            }
        }
    }
    __syncthreads();

    // ---- LN2 (layer 0) -> xr now holds x1
    ln_rows64(sm.xr, ln2g, ln2b, wv, lane);
    __syncthreads();

    // =================== Layer 1: last-token-only path ===================
    for (int h = 0; h < NH_; ++h) {
        // (a) k1, v1 for all 64 tokens; q1 for token 63
        {
            const int d = tid & 31, jg = tid >> 5;
            const float* wk = qkv_w1 + (EE_ + h * HD_ + d) * EE_;
            const float* wvp = qkv_w1 + (2 * EE_ + h * HD_ + d) * EE_;
            float ak[4] = {0.f, 0.f, 0.f, 0.f}, av[4] = {0.f, 0.f, 0.f, 0.f};
            for (int c4 = 0; c4 < 64; ++c4) {
                const float4 wk4 = *(const float4*)(wk + c4 * 4);
                const float4 wv4 = *(const float4*)(wvp + c4 * 4);
#pragma unroll
                for (int k = 0; k < 4; ++k) {
                    const float4 x = *(const float4*)(sm.xr + (jg * 4 + k) * XP + c4 * 4);
                    ak[k] += dot4(x, wk4);
                    av[k] += dot4(x, wv4);
                }
            }
            const float bk = qkv_b1[EE_ + h * HD_ + d];
            const float bv = qkv_b1[2 * EE_ + h * HD_ + d];
#pragma unroll
            for (int k = 0; k < 4; ++k) {
                sm.qs[(jg * 4 + k) * QP + d] = ak[k] + bk;
                sm.kv[(jg * 4 + k) * QP + d] = av[k] + bv;
            }
            if (tid < 32) {
                const float* wq = qkv_w1 + (h * HD_ + tid) * EE_;
                float s = 0.f;
                for (int c4 = 0; c4 < 64; ++c4)
                    s += dot4(*(const float4*)(sm.xr + 63 * XP + c4 * 4),
                              *(const float4*)(wq + c4 * 4));
                sm.q1b[tid] = s + qkv_b1[h * HD_ + tid];
            }
        }
        __syncthreads();
        // scores + softmax (wave 0)
        if (tid < 64) {
            const float4* kk = (const float4*)(sm.qs + tid * QP);
            const float4* qq = (const float4*)sm.q1b;
            float s = 0.f;
#pragma unroll
            for (int c = 0; c < 8; ++c) s += dot4(qq[c], kk[c]);
            s *= SCALE_;
            const float m = wmax(s);
            const float ex = __expf(s - m);
            const float su = wsum(ex);
            sm.sbuf[tid] = ex / su;
        }
        __syncthreads();
        // o1 slice
        if (tid < 32) {
            float acc = 0.f;
            for (int j = 0; j < 64; ++j) acc += sm.sbuf[j] * sm.kv[j * QP + tid];
            sm.o1b[h * HD_ + tid] = acc;
        }
        __syncthreads();
    }

    // attn out proj + residual (token 63)
    if (tid < 256) {
        const int e = tid;
        const float* wrow = aow1 + e * EE_;
        float s = 0.f;
        for (int c4 = 0; c4 < 64; ++c4)
            s += dot4(*(const float4*)(sm.o1b + c4 * 4), *(const float4*)(wrow + c4 * 4));
        sm.x2b[e] = sm.xr[63 * XP + e] + s + aob1[e];
    }
    __syncthreads();
    ln_vec256(sm.x2b, ln1g + EE_, ln1b + EE_, sm.stat, tid);

    // FFN (layer 1, token 63): hidden in U[0..1023]
    {
        const float* wA = f1w1 + tid * EE_;
        const float* wB = f1w1 + (tid + 512) * EE_;
        float s0 = 0.f, s1 = 0.f;
        for (int c4 = 0; c4 < 64; ++c4) {
            const float4 x = *(const float4*)(sm.x2b + c4 * 4);
            s0 += dot4(x, *(const float4*)(wA + c4 * 4));
            s1 += dot4(x, *(const float4*)(wB + c4 * 4));
        }
        sm.U[tid] = silu_f(s0 + f1b1[tid]);
        sm.U[tid + 512] = silu_f(s1 + f1b1[tid + 512]);
    }
    __syncthreads();
    {
        const int g = tid >> 8, e = tid & 255;
        const float* w2r = f2w1 + e * FF_ + g * 512;
        float pacc = 0.f;
        for (int f4 = 0; f4 < 128; ++f4)
            pacc += dot4(*(const float4*)(sm.U + g * 512 + f4 * 4),
                         *(const float4*)(w2r + f4 * 4));
        if (g == 1) sm.qs[e] = pacc;
        __syncthreads();
        if (g == 0) sm.x3b[e] = sm.x2b[e] + pacc + sm.qs[e] + f2b1[e];
    }
    __syncthreads();
    ln_vec256(sm.x3b, ln2g + EE_, ln2b + EE_, sm.stat, tid);

    // head
    if (tid < OUT_) {
        const float* wrow = hw + tid * EE_;
        float s = 0.f;
        for (int c4 = 0; c4 < 64; ++c4)
            s += dot4(*(const float4*)(sm.x3b + c4 * 4), *(const float4*)(wrow + c4 * 4));
        out[n * OUT_ + tid] = s + hb[tid];
    }
}

// ---------------------------------------------------------------------------
extern "C" void kernel_launch(void* const* d_in, const int* in_sizes, int n_in,
                              void* d_out, int out_size, void* d_ws, size_t ws_size,
                              hipStream_t stream) {
    (void)in_sizes; (void)n_in; (void)out_size; (void)ws_size;
    const float* inputs = (const float*)d_in[0];
    const float* embed_w = (const float*)d_in[1];
    const float* embed_b = (const float*)d_in[2];
    const float* qkv_w = (const float*)d_in[3];
    const float* qkv_b = (const float*)d_in[4];
    const float* attn_out_w = (const float*)d_in[5];
    const float* attn_out_b = (const float*)d_in[6];
    const float* ln1_g = (const float*)d_in[7];
    const float* ln1_b = (const float*)d_in[8];
    const float* ffn1_w = (const float*)d_in[9];
    const float* ffn1_b = (const float*)d_in[10];
    const float* ffn2_w = (const float*)d_in[11];
    const float* ffn2_b = (const float*)d_in[12];
    const float* ln2_g = (const float*)d_in[13];
    const float* ln2_b = (const float*)d_in[14];
    const float* head_w = (const float*)d_in[15];
    const float* head_b = (const float*)d_in[16];
    float* out = (float*)d_out;

    float* ws = (float*)d_ws;
    float* emb = ws;                       // 2048*256 floats
    float* qkv_tok = ws + NWIN * EE_;      // 2048*768 floats

    k_embed<<<NWIN, 256, 0, stream>>>(inputs, embed_w, embed_b, emb);
    k_qkv0<<<NWIN, 256, 0, stream>>>(emb, qkv_w, qkv_b, qkv_tok);
    k_fused<<<NWIN, NT, 0, stream>>>(emb, qkv_tok, qkv_w, qkv_b,
                                     attn_out_w, attn_out_b, ln1_g, ln1_b,
                                     ffn1_w, ffn1_b, ffn2_w, ffn2_b,
                                     ln2_g, ln2_b, head_w, head_b, out);
}

// Round 2
// 1828.291 us; speedup vs baseline: 5.6558x; 5.6558x over previous
//
#include <hip/hip_runtime.h>
#include <hip/hip_bf16.h>

// Problem constants
#define BB_ 2
#define SS_ 1024
#define FIN_ 64
#define EE_ 256
#define FF_ 1024
#define NH_ 8
#define HD_ 32
#define OUT_ 10
#define NWIN (BB_ * SS_)
#define NT 512
#define SCALE_ 0.17677669529663687f  // 1/sqrt(32)

#define XP 260    // xr fp32 pitch (words)
#define XBP 264   // xb / hb bf16 pitch (halfwords)

typedef unsigned short u16;
typedef __attribute__((ext_vector_type(8))) short bf8_t;   // 8 x bf16 (4 VGPRs)
typedef __attribute__((ext_vector_type(4))) float f4_t;    // MFMA C/D
#define MFMA_B16(a, b, c) __builtin_amdgcn_mfma_f32_16x16x32_bf16(a, b, c, 0, 0, 0)

union U4 { uint2 u; u16 h[4]; };

__device__ __forceinline__ u16 bf16r(float f) {
    unsigned int u = __builtin_bit_cast(unsigned int, f);
    return (u16)((u + 0x7FFFu + ((u >> 16) & 1u)) >> 16);
}

__device__ __forceinline__ float dot4(float4 a, float4 b) {
    return a.x * b.x + a.y * b.y + a.z * b.z + a.w * b.w;
}

__device__ __forceinline__ float wsum(float v) {
#pragma unroll
    for (int o = 32; o > 0; o >>= 1) v += __shfl_xor(v, o, 64);
    return v;
}

__device__ __forceinline__ float wmax(float v) {
#pragma unroll
    for (int o = 32; o > 0; o >>= 1) v = fmaxf(v, __shfl_xor(v, o, 64));
    return v;
}

__device__ __forceinline__ float silu_f(float h) { return h / (1.f + __expf(-h)); }

// ---------------------------------------------------------------------------
// fp32 -> bf16 conversion kernel (weights into workspace)
// ---------------------------------------------------------------------------
__global__ void k_cvt(const float* __restrict__ src, u16* __restrict__ dst, int n) {
    for (int i = blockIdx.x * 256 + threadIdx.x; i < n; i += gridDim.x * 256)
        dst[i] = bf16r(src[i]);
}

// ---------------------------------------------------------------------------
// Kernel 1: emb[t, e] = inputs[t, :] @ embed_w[e, :] + embed_b[e]
// ---------------------------------------------------------------------------
__global__ void k_embed(const float* __restrict__ in, const float* __restrict__ w,
                        const float* __restrict__ bias, float* __restrict__ emb) {
    __shared__ float row[FIN_];
    const int t = blockIdx.x;
    if (threadIdx.x < FIN_) row[threadIdx.x] = in[t * FIN_ + threadIdx.x];
    __syncthreads();
    const int e = threadIdx.x;
    const float4* w4 = (const float4*)(w + e * FIN_);
    const float4* r4 = (const float4*)row;
    float s = 0.f;
#pragma unroll
    for (int c = 0; c < FIN_ / 4; ++c) s += dot4(w4[c], r4[c]);
    emb[t * EE_ + e] = s + bias[e];
}

// ---------------------------------------------------------------------------
// Kernel 2: qkv_tok_b[t, j] = bf16(emb[t, :] @ qkv_w0[j, :] + qkv_b0[j])
// ---------------------------------------------------------------------------
__global__ void k_qkv0(const float* __restrict__ emb, const float* __restrict__ qkvw,
                       const float* __restrict__ qkvb, u16* __restrict__ qkv) {
    __shared__ float row[EE_];
    const int t = blockIdx.x;
    row[threadIdx.x] = emb[t * EE_ + threadIdx.x];
    __syncthreads();
    const float4* r4 = (const float4*)row;
    for (int j = threadIdx.x; j < 3 * EE_; j += 256) {
        const float4* w4 = (const float4*)(qkvw + j * EE_);
        float s = 0.f;
#pragma unroll 8
        for (int c = 0; c < EE_ / 4; ++c) s += dot4(w4[c], r4[c]);
        qkv[t * 3 * EE_ + j] = bf16r(s + qkvb[j]);
    }
}

// ---------------------------------------------------------------------------
// Fused per-window kernel (2048 blocks x 512 threads, MFMA bf16)
// ---------------------------------------------------------------------------
struct __align__(16) SMem {
    float xr[64 * XP];   // fp32 window state (residual accumulator)   66,560 B
    u16 xb[64 * XBP];    // bf16 copy of x (MFMA A operand)            33,792 B
    union {
        struct {                       // attention head-pair phase
            u16 qb[2][64 * 40];        // 10,240 B
            u16 kb[2][64 * 40];        // 10,240 B
            u16 vtb[2][32 * 72];       //  9,216 B  (V transposed: [d][token])
            u16 pb[2][64 * 72];        // 18,432 B  (softmax probs, row-major)
            u16 opair[64 * 72];        //  9,216 B  (O for the 2 heads)
        } att;
        struct { u16 hb[64 * XBP]; } ffn;          // 33,792 B (hidden chunk)
        struct {                                    // layer-1 tail
            float k1p[64 * 68];        // 17,408 B
            float v1p[64 * 68];        // 17,408 B
            float hid1[1024];          //  4,096 B
        } tail;
    } u;                                            // 57,344 B
    float sbuf2[128];
    float q1b[64];
    float o1b[256];
    float x2b[256];
    float x3b[256];
    float stat[4];
};

__device__ __forceinline__ void ln_rows64(float* xr, u16* xb, const float* __restrict__ g,
                                          const float* __restrict__ b, int wv, int lane) {
    const float g0 = g[lane], g1 = g[lane + 64], g2 = g[lane + 128], g3 = g[lane + 192];
    const float b0 = b[lane], b1 = b[lane + 64], b2 = b[lane + 128], b3 = b[lane + 192];
    for (int r = 0; r < 8; ++r) {
        float* row = xr + (wv * 8 + r) * XP;
        u16* xrow = xb + (wv * 8 + r) * XBP;
        float v0 = row[lane], v1 = row[lane + 64], v2 = row[lane + 128], v3 = row[lane + 192];
        const float m = wsum(v0 + v1 + v2 + v3) * 0.00390625f;
        const float d0 = v0 - m, d1 = v1 - m, d2 = v2 - m, d3 = v3 - m;
        const float var = wsum(d0 * d0 + d1 * d1 + d2 * d2 + d3 * d3) * 0.00390625f;
        const float rs = rsqrtf(var + 1e-5f);
        const float o0 = d0 * rs * g0 + b0, o1 = d1 * rs * g1 + b1;
        const float o2 = d2 * rs * g2 + b2, o3 = d3 * rs * g3 + b3;
        row[lane] = o0; row[lane + 64] = o1; row[lane + 128] = o2; row[lane + 192] = o3;
        xrow[lane] = bf16r(o0); xrow[lane + 64] = bf16r(o1);
        xrow[lane + 128] = bf16r(o2); xrow[lane + 192] = bf16r(o3);
    }
}

__device__ __forceinline__ void ln_vec256(float* buf, const float* __restrict__ g,
                                          const float* __restrict__ b, float* stat, int tid) {
    if (tid < 64) {
        const float a0 = buf[tid], a1 = buf[tid + 64], a2 = buf[tid + 128], a3 = buf[tid + 192];
        const float m = wsum(a0 + a1 + a2 + a3) * 0.00390625f;
        const float d0 = a0 - m, d1 = a1 - m, d2 = a2 - m, d3 = a3 - m;
        const float var = wsum(d0 * d0 + d1 * d1 + d2 * d2 + d3 * d3) * 0.00390625f;
        if (tid == 0) { stat[0] = m; stat[1] = rsqrtf(var + 1e-5f); }
    }
    __syncthreads();
    if (tid < 256) {
        const float m = stat[0], rs = stat[1];
        buf[tid] = (buf[tid] - m) * rs * g[tid] + b[tid];
    }
    __syncthreads();
}

__global__ __launch_bounds__(NT) void k_fused(
    const float* __restrict__ emb, const u16* __restrict__ qkvtb,
    const u16* __restrict__ qb0c,                                   // bf16 qkv_b layer0
    const u16* __restrict__ w1b, const u16* __restrict__ w2b,       // bf16 ffn weights L0
    const u16* __restrict__ wob, const u16* __restrict__ wkvb,      // bf16 Wo L0, Wkv L1
    const float* __restrict__ qkv_w, const float* __restrict__ qkv_b,
    const float* __restrict__ aow, const float* __restrict__ aob,
    const float* __restrict__ ln1g, const float* __restrict__ ln1b,
    const float* __restrict__ f1w, const float* __restrict__ f1b,
    const float* __restrict__ f2w, const float* __restrict__ f2b,
    const float* __restrict__ ln2g, const float* __restrict__ ln2b,
    const float* __restrict__ hw, const float* __restrict__ hb,
    float* __restrict__ out) {
    __shared__ SMem sm;
    const int n = blockIdx.x;
    const int bb = n >> 10, p = n & 1023;
    const int tid = threadIdx.x;
    const int lane = tid & 63, wv = tid >> 6;
    const int col = lane & 15, quad = lane >> 4;

    // Layer-1 fp32 parameter bases (tail path)
    const float* qkv_w1 = qkv_w + 3 * EE_ * EE_;
    const float* qkv_b1 = qkv_b + 3 * EE_;
    const float* aow1 = aow + EE_ * EE_;
    const float* aob1 = aob + EE_;
    const float* f1w1 = f1w + FF_ * EE_;
    const float* f1b1 = f1b + FF_;
    const float* f2w1 = f2w + EE_ * FF_;
    const float* f2b1 = f2b + EE_;

    // ---- init xr = x0 (gathered emb, zeros for pads) + attn_out_b[0]
    for (int idx = tid; idx < 64 * EE_; idx += NT) {
        const int i = idx >> 8, e = idx & 255;
        const int t = p - 63 + i;
        const float v = (t >= 0) ? emb[((bb << 10) + t) * EE_ + e] : 0.f;
        sm.xr[i * XP + e] = v + aob[e];
    }

    // =================== Layer 0 attention (MFMA, head pairs) ===================
    f4_t pacc[2][4];
#pragma unroll
    for (int a = 0; a < 2; ++a)
#pragma unroll
        for (int m = 0; m < 4; ++m) pacc[a][m] = (f4_t){0.f, 0.f, 0.f, 0.f};

    for (int hp = 0; hp < 4; ++hp) {
        // (a) cooperative gather: q,k row-major bf16; v transposed
        {
            const int i = tid >> 3, dg = tid & 7;
            const int t = p - 63 + i;
            const u16* src = (t >= 0) ? (qkvtb + (size_t)((bb << 10) + t) * 768) : qb0c;
#pragma unroll
            for (int hh = 0; hh < 2; ++hh) {
                const u16* s2 = src + (hp * 2 + hh) * HD_ + dg * 4;
                *(uint2*)(sm.u.att.qb[hh] + i * 40 + dg * 4) = *(const uint2*)(s2);
                *(uint2*)(sm.u.att.kb[hh] + i * 40 + dg * 4) = *(const uint2*)(s2 + EE_);
                U4 v4; v4.u = *(const uint2*)(s2 + 2 * EE_);
#pragma unroll
                for (int c = 0; c < 4; ++c)
                    sm.u.att.vtb[hh][(dg * 4 + c) * 72 + i] = v4.h[c];
            }
        }
        __syncthreads();
        // (b) per-wave: scores MFMA -> in-register softmax -> P -> PV MFMA -> opair
        {
            const int hh = wv >> 2, mt = wv & 3;
            const u16* qbh = sm.u.att.qb[hh];
            const u16* kbh = sm.u.att.kb[hh];
            const bf8_t aq = *(const bf8_t*)(qbh + (mt * 16 + col) * 40 + quad * 8);
            f4_t sc[4];
#pragma unroll
            for (int nt = 0; nt < 4; ++nt) {
                const bf8_t bk = *(const bf8_t*)(kbh + (nt * 16 + col) * 40 + quad * 8);
                f4_t z = {0.f, 0.f, 0.f, 0.f};
                sc[nt] = MFMA_B16(aq, bk, z);
            }
#pragma unroll
            for (int j = 0; j < 4; ++j) {
                float s0 = sc[0][j] * SCALE_, s1 = sc[1][j] * SCALE_;
                float s2v = sc[2][j] * SCALE_, s3 = sc[3][j] * SCALE_;
                float m = fmaxf(fmaxf(s0, s1), fmaxf(s2v, s3));
                m = fmaxf(m, __shfl_xor(m, 1)); m = fmaxf(m, __shfl_xor(m, 2));
                m = fmaxf(m, __shfl_xor(m, 4)); m = fmaxf(m, __shfl_xor(m, 8));
                const float e0 = __expf(s0 - m), e1 = __expf(s1 - m);
                const float e2 = __expf(s2v - m), e3 = __expf(s3 - m);
                float s = e0 + e1 + e2 + e3;
                s += __shfl_xor(s, 1); s += __shfl_xor(s, 2);
                s += __shfl_xor(s, 4); s += __shfl_xor(s, 8);
                const float inv = 1.f / s;
                sc[0][j] = e0 * inv; sc[1][j] = e1 * inv;
                sc[2][j] = e2 * inv; sc[3][j] = e3 * inv;
            }
            u16* pbh = sm.u.att.pb[hh];
            const int r0 = mt * 16 + quad * 4;
#pragma unroll
            for (int nt = 0; nt < 4; ++nt)
#pragma unroll
                for (int j = 0; j < 4; ++j)
                    pbh[(r0 + j) * 72 + nt * 16 + col] = bf16r(sc[nt][j]);
            // PV: same wave wrote all 64 cols of its 16 rows -> no barrier needed
            f4_t ov[2];
            ov[0] = (f4_t){0.f, 0.f, 0.f, 0.f}; ov[1] = (f4_t){0.f, 0.f, 0.f, 0.f};
#pragma unroll
            for (int ks = 0; ks < 2; ++ks) {
                const bf8_t ap = *(const bf8_t*)(pbh + (mt * 16 + col) * 72 + ks * 32 + quad * 8);
#pragma unroll
                for (int ntl = 0; ntl < 2; ++ntl) {
                    const bf8_t bv = *(const bf8_t*)(sm.u.att.vtb[hh] +
                                                     (ntl * 16 + col) * 72 + ks * 32 + quad * 8);
                    ov[ntl] = MFMA_B16(ap, bv, ov[ntl]);
                }
            }
#pragma unroll
            for (int ntl = 0; ntl < 2; ++ntl)
#pragma unroll
                for (int j = 0; j < 4; ++j)
                    sm.u.att.opair[(r0 + j) * 72 + hh * 32 + ntl * 16 + col] = bf16r(ov[ntl][j]);
        }
        __syncthreads();
        // (c) proj accumulate: pacc += O_pair @ Wo_slice^T
#pragma unroll
        for (int ks = 0; ks < 2; ++ks) {
            bf8_t ao[4];
#pragma unroll
            for (int mt = 0; mt < 4; ++mt)
                ao[mt] = *(const bf8_t*)(sm.u.att.opair + (mt * 16 + col) * 72 + ks * 32 + quad * 8);
#pragma unroll
            for (int ntl = 0; ntl < 2; ++ntl) {
                const bf8_t bw = *(const bf8_t*)(wob + ((wv * 2 + ntl) * 16 + col) * EE_ +
                                                 hp * 64 + ks * 32 + quad * 8);
#pragma unroll
                for (int mt = 0; mt < 4; ++mt) pacc[ntl][mt] = MFMA_B16(ao[mt], bw, pacc[ntl][mt]);
            }
        }
        __syncthreads();
    }
    // fold proj into xr
#pragma unroll
    for (int ntl = 0; ntl < 2; ++ntl)
#pragma unroll
        for (int mt = 0; mt < 4; ++mt)
#pragma unroll
            for (int j = 0; j < 4; ++j)
                sm.xr[(mt * 16 + quad * 4 + j) * XP + wv * 32 + ntl * 16 + col] += pacc[ntl][mt][j];
    __syncthreads();

    // ---- LN1 -> xr fp32 + xb bf16
    ln_rows64(sm.xr, sm.xb, ln1g, ln1b, wv, lane);
    __syncthreads();

    // ---- FFN (MFMA, f-chunked 4 x 256)
    f4_t facc[2][4];
#pragma unroll
    for (int a = 0; a < 2; ++a)
#pragma unroll
        for (int m = 0; m < 4; ++m) facc[a][m] = (f4_t){0.f, 0.f, 0.f, 0.f};

    for (int c = 0; c < 4; ++c) {
        {   // FFN1 -> silu -> hb (bf16)
            f4_t hacc[2][4];
#pragma unroll
            for (int a = 0; a < 2; ++a)
#pragma unroll
                for (int m = 0; m < 4; ++m) hacc[a][m] = (f4_t){0.f, 0.f, 0.f, 0.f};
#pragma unroll 2
            for (int ks = 0; ks < 8; ++ks) {
                bf8_t ax[4];
#pragma unroll
                for (int mt = 0; mt < 4; ++mt)
                    ax[mt] = *(const bf8_t*)(sm.xb + (mt * 16 + col) * XBP + ks * 32 + quad * 8);
#pragma unroll
                for (int ntl = 0; ntl < 2; ++ntl) {
                    const int f = (c * 16 + wv * 2 + ntl) * 16 + col;
                    const bf8_t bw = *(const bf8_t*)(w1b + f * EE_ + ks * 32 + quad * 8);
#pragma unroll
                    for (int mt = 0; mt < 4; ++mt) hacc[ntl][mt] = MFMA_B16(ax[mt], bw, hacc[ntl][mt]);
                }
            }
#pragma unroll
            for (int ntl = 0; ntl < 2; ++ntl) {
                const int f = (c * 16 + wv * 2 + ntl) * 16 + col;
                const float bv = f1b[f];
                const int lc = (wv * 2 + ntl) * 16 + col;
#pragma unroll
                for (int mt = 0; mt < 4; ++mt)
#pragma unroll
                    for (int j = 0; j < 4; ++j) {
                        const float hv = hacc[ntl][mt][j] + bv;
                        sm.u.ffn.hb[(mt * 16 + quad * 4 + j) * XBP + lc] = bf16r(silu_f(hv));
                    }
            }
        }
        __syncthreads();
        {   // FFN2 accumulate
#pragma unroll 2
            for (int ks = 0; ks < 8; ++ks) {
                bf8_t ah[4];
#pragma unroll
                for (int mt = 0; mt < 4; ++mt)
                    ah[mt] = *(const bf8_t*)(sm.u.ffn.hb + (mt * 16 + col) * XBP + ks * 32 + quad * 8);
#pragma unroll
                for (int ntl = 0; ntl < 2; ++ntl) {
                    const int e = (wv * 2 + ntl) * 16 + col;
                    const bf8_t bw = *(const bf8_t*)(w2b + e * FF_ + c * 256 + ks * 32 + quad * 8);
#pragma unroll
                    for (int mt = 0; mt < 4; ++mt) facc[ntl][mt] = MFMA_B16(ah[mt], bw, facc[ntl][mt]);
                }
            }
        }
        __syncthreads();
    }
    // fold FFN2 + bias into xr
#pragma unroll
    for (int ntl = 0; ntl < 2; ++ntl) {
        const int e = wv * 32 + ntl * 16 + col;
        const float b2 = f2b[e];
#pragma unroll
        for (int mt = 0; mt < 4; ++mt)
#pragma unroll
            for (int j = 0; j < 4; ++j)
                sm.xr[(mt * 16 + quad * 4 + j) * XP + e] += facc[ntl][mt][j] + b2;
    }
    __syncthreads();

    // ---- LN2 -> x1 (fp32 in xr, bf16 in xb)
    ln_rows64(sm.xr, sm.xb, ln2g, ln2b, wv, lane);
    __syncthreads();

    // =================== Layer 1 (last-token path, K/V via MFMA) ===================
    for (int hp = 0; hp < 4; ++hp) {
        {   // K1/V1 MFMA for the pair's 2 heads (128 output cols)
            const int half = wv >> 2, mt = wv & 3;
            f4_t kacc[4];
#pragma unroll
            for (int a = 0; a < 4; ++a) kacc[a] = (f4_t){0.f, 0.f, 0.f, 0.f};
#pragma unroll 2
            for (int ks = 0; ks < 8; ++ks) {
                const bf8_t ax = *(const bf8_t*)(sm.xb + (mt * 16 + col) * XBP + ks * 32 + quad * 8);
#pragma unroll
                for (int ntl = 0; ntl < 4; ++ntl) {
                    const int wr = half * EE_ + hp * 64 + ntl * 16 + col;
                    const bf8_t bw = *(const bf8_t*)(wkvb + wr * EE_ + ks * 32 + quad * 8);
                    kacc[ntl] = MFMA_B16(ax, bw, kacc[ntl]);
                }
            }
            float* dst = half ? sm.u.tail.v1p : sm.u.tail.k1p;
#pragma unroll
            for (int ntl = 0; ntl < 4; ++ntl) {
                const int cc = ntl * 16 + col;
                const float bs = qkv_b1[(half + 1) * EE_ + hp * 64 + cc];
#pragma unroll
                for (int j = 0; j < 4; ++j)
                    dst[(mt * 16 + quad * 4 + j) * 68 + cc] = kacc[ntl][j] + bs;
            }
        }
        // q1 for token 63 (fp32 VALU, 64 threads)
        if (tid < 64) {
            const float* wq = qkv_w1 + (hp * 64 + tid) * EE_;
            float s = 0.f;
#pragma unroll 8
            for (int c4 = 0; c4 < 64; ++c4)
                s += dot4(*(const float4*)(sm.xr + 63 * XP + c4 * 4),
                          *(const float4*)(wq + c4 * 4));
            sm.q1b[tid] = s + qkv_b1[hp * 64 + tid];
        }
        __syncthreads();
        // scores + softmax for 2 heads (2 waves)
        if (tid < 128) {
            const int hh = tid >> 6, j = tid & 63;
            const float* kr = sm.u.tail.k1p + j * 68 + hh * 32;
            const float* qv = sm.q1b + hh * 32;
            float s = 0.f;
#pragma unroll
            for (int d = 0; d < 32; ++d) s += qv[d] * kr[d];
            s *= SCALE_;
            const float m = wmax(s);
            const float e = __expf(s - m);
            const float su = wsum(e);
            sm.sbuf2[hh * 64 + j] = e / su;
        }
        __syncthreads();
        // o1 slices
        if (tid < 64) {
            const int hh = tid >> 5, d = tid & 31;
            float acc = 0.f;
            for (int j = 0; j < 64; ++j)
                acc += sm.sbuf2[hh * 64 + j] * sm.u.tail.v1p[j * 68 + hh * 32 + d];
            sm.o1b[hp * 64 + hh * 32 + d] = acc;
        }
        __syncthreads();
    }

    // attn out proj + residual (token 63)
    if (tid < 256) {
        const float* wrow = aow1 + tid * EE_;
        float s = 0.f;
#pragma unroll 8
        for (int c4 = 0; c4 < 64; ++c4)
            s += dot4(*(const float4*)(sm.o1b + c4 * 4), *(const float4*)(wrow + c4 * 4));
        sm.x2b[tid] = sm.xr[63 * XP + tid] + s + aob1[tid];
    }
    __syncthreads();
    ln_vec256(sm.x2b, ln1g + EE_, ln1b + EE_, sm.stat, tid);

    // FFN (layer 1, token 63)
    {
        const float* wA = f1w1 + tid * EE_;
        const float* wB = f1w1 + (tid + 512) * EE_;
        float s0 = 0.f, s1 = 0.f;
#pragma unroll 8
        for (int c4 = 0; c4 < 64; ++c4) {
            const float4 x = *(const float4*)(sm.x2b + c4 * 4);
            s0 += dot4(x, *(const float4*)(wA + c4 * 4));
            s1 += dot4(x, *(const float4*)(wB + c4 * 4));
        }
        sm.u.tail.hid1[tid] = silu_f(s0 + f1b1[tid]);
        sm.u.tail.hid1[tid + 512] = silu_f(s1 + f1b1[tid + 512]);
    }
    __syncthreads();
    {
        const int g = tid >> 8, e = tid & 255;
        const float* w2r = f2w1 + e * FF_ + g * 512;
        float pa = 0.f;
#pragma unroll 8
        for (int f4 = 0; f4 < 128; ++f4)
            pa += dot4(*(const float4*)(sm.u.tail.hid1 + g * 512 + f4 * 4),
                       *(const float4*)(w2r + f4 * 4));
        if (g == 1) sm.o1b[e] = pa;
        __syncthreads();
        if (g == 0) sm.x3b[e] = sm.x2b[e] + pa + sm.o1b[e] + f2b1[e];
    }
    __syncthreads();
    ln_vec256(sm.x3b, ln2g + EE_, ln2b + EE_, sm.stat, tid);

    // head
    if (tid < OUT_) {
        const float* wrow = hw + tid * EE_;
        float s = 0.f;
#pragma unroll 8
        for (int c4 = 0; c4 < 64; ++c4)
            s += dot4(*(const float4*)(sm.x3b + c4 * 4), *(const float4*)(wrow + c4 * 4));
        out[n * OUT_ + tid] = s + hb[tid];
    }
}

// ---------------------------------------------------------------------------
extern "C" void kernel_launch(void* const* d_in, const int* in_sizes, int n_in,
                              void* d_out, int out_size, void* d_ws, size_t ws_size,
                              hipStream_t stream) {
    (void)in_sizes; (void)n_in; (void)out_size; (void)ws_size;
    const float* inputs = (const float*)d_in[0];
    const float* embed_w = (const float*)d_in[1];
    const float* embed_b = (const float*)d_in[2];
    const float* qkv_w = (const float*)d_in[3];
    const float* qkv_b = (const float*)d_in[4];
    const float* attn_out_w = (const float*)d_in[5];
    const float* attn_out_b = (const float*)d_in[6];
    const float* ln1_g = (const float*)d_in[7];
    const float* ln1_b = (const float*)d_in[8];
    const float* ffn1_w = (const float*)d_in[9];
    const float* ffn1_b = (const float*)d_in[10];
    const float* ffn2_w = (const float*)d_in[11];
    const float* ffn2_b = (const float*)d_in[12];
    const float* ln2_g = (const float*)d_in[13];
    const float* ln2_b = (const float*)d_in[14];
    const float* head_w = (const float*)d_in[15];
    const float* head_b = (const float*)d_in[16];
    float* out = (float*)d_out;

    char* wsb = (char*)d_ws;
    float* emb = (float*)wsb;                               // 2,097,152 B
    u16* qkvtb = (u16*)(wsb + 2097152);                     // 3,145,728 B
    u16* w1b  = (u16*)(wsb + 5242880);                      //   524,288 B
    u16* w2b  = (u16*)(wsb + 5767168);                      //   524,288 B
    u16* wob  = (u16*)(wsb + 6291456);                      //   131,072 B
    u16* wkvb = (u16*)(wsb + 6422528);                      //   262,144 B
    u16* qb0c = (u16*)(wsb + 6684672);                      //     1,536 B

    // bf16 weight conversion
    k_cvt<<<256, 256, 0, stream>>>(ffn1_w, w1b, FF_ * EE_);
    k_cvt<<<256, 256, 0, stream>>>(ffn2_w, w2b, EE_ * FF_);
    k_cvt<<<64, 256, 0, stream>>>(attn_out_w, wob, EE_ * EE_);
    k_cvt<<<128, 256, 0, stream>>>(qkv_w + 3 * EE_ * EE_ + EE_ * EE_, wkvb, 2 * EE_ * EE_);
    k_cvt<<<1, 256, 0, stream>>>(qkv_b, qb0c, 3 * EE_);

    k_embed<<<NWIN, 256, 0, stream>>>(inputs, embed_w, embed_b, emb);
    k_qkv0<<<NWIN, 256, 0, stream>>>(emb, qkv_w, qkv_b, qkvtb);
    k_fused<<<NWIN, NT, 0, stream>>>(emb, qkvtb, qb0c, w1b, w2b, wob, wkvb,
                                     qkv_w, qkv_b, attn_out_w, attn_out_b,
                                     ln1_g, ln1_b, ffn1_w, ffn1_b, ffn2_w, ffn2_b,
                                     ln2_g, ln2_b, head_w, head_b, out);
}

// Round 3
// 983.087 us; speedup vs baseline: 10.5183x; 1.8597x over previous
//
#include <hip/hip_runtime.h>
#include <hip/hip_bf16.h>

// Problem constants
#define BB_ 2
#define SS_ 1024
#define FIN_ 64
#define EE_ 256
#define FF_ 1024
#define NH_ 8
#define HD_ 32
#define OUT_ 10
#define NWIN (BB_ * SS_)
#define NT 512
#define SCALE_ 0.17677669529663687f  // 1/sqrt(32)
#define XBP 264                      // bf16 A-operand pitch (halfwords)

typedef unsigned short u16;
typedef unsigned int u32;
typedef __attribute__((ext_vector_type(8))) short bf8_t;   // 8 x bf16 (4 VGPRs)
typedef __attribute__((ext_vector_type(4))) float f4_t;    // MFMA C/D
#define MFMA_B16(a, b, c) __builtin_amdgcn_mfma_f32_16x16x32_bf16(a, b, c, 0, 0, 0)

union U4 { uint2 u; u16 h[4]; };

__device__ __forceinline__ u16 bf16r(float f) {
    u32 u = __builtin_bit_cast(u32, f);
    return (u16)((u + 0x7FFFu + ((u >> 16) & 1u)) >> 16);
}
__device__ __forceinline__ float b2f(u16 h) {
    return __builtin_bit_cast(float, ((u32)h) << 16);
}
__device__ __forceinline__ float b2f_lo(u32 u) {
    return __builtin_bit_cast(float, u << 16);
}
__device__ __forceinline__ float b2f_hi(u32 u) {
    return __builtin_bit_cast(float, u & 0xFFFF0000u);
}

__device__ __forceinline__ float dot4(float4 a, float4 b) {
    return a.x * b.x + a.y * b.y + a.z * b.z + a.w * b.w;
}
__device__ __forceinline__ float wsum(float v) {
#pragma unroll
    for (int o = 32; o > 0; o >>= 1) v += __shfl_xor(v, o, 64);
    return v;
}
__device__ __forceinline__ float wmax(float v) {
#pragma unroll
    for (int o = 32; o > 0; o >>= 1) v = fmaxf(v, __shfl_xor(v, o, 64));
    return v;
}
__device__ __forceinline__ float silu_f(float h) { return h / (1.f + __expf(-h)); }

// ---------------------------------------------------------------------------
// One-shot fp32 -> bf16 conversion of all weight segments
// ---------------------------------------------------------------------------
struct CvtArgs {
    const float* s[10];
    u16* d[10];
    int n[10];
};
__global__ void k_cvt_all(CvtArgs a) {
#pragma unroll 1
    for (int seg = 0; seg < 10; ++seg) {
        const float* __restrict__ src = a.s[seg];
        u16* __restrict__ dst = a.d[seg];
        const int nn = a.n[seg];
        for (int i = blockIdx.x * 256 + threadIdx.x; i < nn; i += gridDim.x * 256)
            dst[i] = bf16r(src[i]);
    }
}

// ---------------------------------------------------------------------------
// Kernel 1: emb[t, e] = inputs[t, :] @ embed_w[e, :] + embed_b[e]
// ---------------------------------------------------------------------------
__global__ void k_embed(const float* __restrict__ in, const float* __restrict__ w,
                        const float* __restrict__ bias, float* __restrict__ emb) {
    __shared__ float row[FIN_];
    const int t = blockIdx.x;
    if (threadIdx.x < FIN_) row[threadIdx.x] = in[t * FIN_ + threadIdx.x];
    __syncthreads();
    const int e = threadIdx.x;
    const float4* w4 = (const float4*)(w + e * FIN_);
    const float4* r4 = (const float4*)row;
    float s = 0.f;
#pragma unroll
    for (int c = 0; c < FIN_ / 4; ++c) s += dot4(w4[c], r4[c]);
    emb[t * EE_ + e] = s + bias[e];
}

// ---------------------------------------------------------------------------
// Kernel 2 (MFMA): qkv_tok[t, :] = emb[t, :] @ qkv_w0^T + qkv_b0, bf16 out
// grid = 128 blocks x 16 tokens, block = 512
// ---------------------------------------------------------------------------
__global__ __launch_bounds__(512) void k_qkv0m(const float* __restrict__ emb,
                                               const u16* __restrict__ wq0b,
                                               const float* __restrict__ qkvb,
                                               u16* __restrict__ qkvtb) {
    __shared__ u16 ab[16 * XBP];
    const int b = blockIdx.x;
    const int tid = threadIdx.x, lane = tid & 63, wv = tid >> 6;
    const int col = lane & 15, quad = lane >> 4;
    for (int idx = tid; idx < 16 * 256; idx += 512) {
        const int i = idx >> 8, e = idx & 255;
        ab[i * XBP + e] = bf16r(emb[(b * 16 + i) * EE_ + e]);
    }
    __syncthreads();
    f4_t acc[6];
#pragma unroll
    for (int nt = 0; nt < 6; ++nt) acc[nt] = (f4_t){0.f, 0.f, 0.f, 0.f};
#pragma unroll
    for (int ks = 0; ks < 8; ++ks) {
        const bf8_t ax = *(const bf8_t*)(ab + col * XBP + ks * 32 + quad * 8);
#pragma unroll
        for (int nt = 0; nt < 6; ++nt) {
            const int r = wv * 96 + nt * 16 + col;
            const bf8_t bw = *(const bf8_t*)(wq0b + r * EE_ + ks * 32 + quad * 8);
            acc[nt] = MFMA_B16(ax, bw, acc[nt]);
        }
    }
#pragma unroll
    for (int nt = 0; nt < 6; ++nt) {
        const int cc = wv * 96 + nt * 16 + col;
        const float bs = qkvb[cc];
#pragma unroll
        for (int j = 0; j < 4; ++j) {
            const int tok = b * 16 + quad * 4 + j;
            qkvtb[tok * 768 + cc] = bf16r(acc[nt][j] + bs);
        }
    }
}

// ---------------------------------------------------------------------------
// Fused per-window kernel: 2048 blocks x 512 threads, LDS <= 80 KB (2 blk/CU)
// ---------------------------------------------------------------------------
struct __align__(16) SMem {
    u16 xb[64 * XBP];                              // 33,792 B  bf16 A operand
    union {
        struct {                                   // attention head-pair phase
            u16 qbop[5120];   // qb[2][64*40]  OR opair[64*72]
            u16 kbpb[9216];   // kb[2][64*40]  OR pb[2][64*72]
            u16 vtb[4608];    // vt[2][32*72]
        } att;                                     // 37,888 B
        struct { u16 hb[64 * XBP]; } ffn;          // 33,792 B
        struct { float k1p[64 * 68]; float v1p[64 * 68]; } tail;  // 34,816 B
    } u;
    float lnred[64 * 17];                          // 4,352 B
    float lnstat[128];                             //   512 B
    float x1row[256];                              // 1,024 B
    float q1b[64];                                 //   256 B
    float sbuf2[128];                              //   512 B
    float o1b[256];                                // 1,024 B
};                                                 // total ~79,360 B

// Register-resident LayerNorm over C-frag-layout state x[ntl][mt][j].
// Writes bf16 xb; leaves normalized fp32 in x. Caller must __syncthreads()
// after return before reading xb from other waves.
__device__ __forceinline__ void reg_ln(float (&x)[2][4][4], SMem& sm,
                                       float gc0, float gc1, float bc0, float bc1,
                                       int tid, int wv, int col, int quad,
                                       int colg0, int colg1) {
    float ps[4][4], pq[4][4];
#pragma unroll
    for (int mt = 0; mt < 4; ++mt)
#pragma unroll
        for (int j = 0; j < 4; ++j) {
            const float v0 = x[0][mt][j], v1 = x[1][mt][j];
            ps[mt][j] = v0 + v1;
            pq[mt][j] = v0 * v0 + v1 * v1;
        }
#pragma unroll
    for (int o = 1; o < 16; o <<= 1) {
#pragma unroll
        for (int mt = 0; mt < 4; ++mt)
#pragma unroll
            for (int j = 0; j < 4; ++j) {
                ps[mt][j] += __shfl_xor(ps[mt][j], o);
                pq[mt][j] += __shfl_xor(pq[mt][j], o);
            }
    }
    if (col == 0) {
#pragma unroll
        for (int mt = 0; mt < 4; ++mt)
#pragma unroll
            for (int j = 0; j < 4; ++j) {
                const int row = mt * 16 + quad * 4 + j;
                sm.lnred[row * 17 + wv * 2] = ps[mt][j];
                sm.lnred[row * 17 + wv * 2 + 1] = pq[mt][j];
            }
    }
    __syncthreads();
    if (tid < 64) {
        float s = 0.f, q = 0.f;
#pragma unroll
        for (int w = 0; w < 8; ++w) {
            s += sm.lnred[tid * 17 + w * 2];
            q += sm.lnred[tid * 17 + w * 2 + 1];
        }
        const float m = s * 0.00390625f;
        const float var = q * 0.00390625f - m * m;
        sm.lnstat[tid * 2] = m;
        sm.lnstat[tid * 2 + 1] = rsqrtf(var + 1e-5f);
    }
    __syncthreads();
#pragma unroll
    for (int mt = 0; mt < 4; ++mt)
#pragma unroll
        for (int j = 0; j < 4; ++j) {
            const int row = mt * 16 + quad * 4 + j;
            const float m = sm.lnstat[row * 2];
            const float rs = sm.lnstat[row * 2 + 1];
            const float xn0 = (x[0][mt][j] - m) * rs * gc0 + bc0;
            const float xn1 = (x[1][mt][j] - m) * rs * gc1 + bc1;
            x[0][mt][j] = xn0;
            x[1][mt][j] = xn1;
            sm.xb[row * XBP + colg0] = bf16r(xn0);
            sm.xb[row * XBP + colg1] = bf16r(xn1);
        }
}

__global__ __launch_bounds__(NT, 4) void k_fused(
    const float* __restrict__ emb, const u16* __restrict__ qkvtb,
    const u16* __restrict__ qb0c,
    const u16* __restrict__ w1b, const u16* __restrict__ w2b,
    const u16* __restrict__ wob, const u16* __restrict__ wkvb,
    const u16* __restrict__ wq1b, const u16* __restrict__ wob1,
    const float* __restrict__ qkv_b, const float* __restrict__ aob,
    const float* __restrict__ ln1g, const float* __restrict__ ln1b,
    const float* __restrict__ f1b, const float* __restrict__ f2b,
    const float* __restrict__ ln2g, const float* __restrict__ ln2b,
    float* __restrict__ x2g) {
    __shared__ SMem sm;
    const int n = blockIdx.x;
    const int bb = n >> 10, p = n & 1023;
    const int tid = threadIdx.x;
    const int lane = tid & 63, wv = tid >> 6;
    const int col = lane & 15, quad = lane >> 4;
    const int colg0 = wv * 32 + col, colg1 = colg0 + 16;

    const float* qkv_b1 = qkv_b + 3 * EE_;
    const float* aob1p = aob + EE_;

    // per-thread column scalars
    const float aob_0 = aob[colg0], aob_1 = aob[colg1];
    const float f2b_0 = f2b[colg0], f2b_1 = f2b[colg1];
    const float g1_0 = ln1g[colg0], g1_1 = ln1g[colg1];
    const float b1_0 = ln1b[colg0], b1_1 = ln1b[colg1];
    const float g2_0 = ln2g[colg0], g2_1 = ln2g[colg1];
    const float b2_0 = ln2b[colg0], b2_1 = ln2b[colg1];

    // =================== Layer 0 attention (MFMA, head pairs) ===================
    f4_t pacc[2][4];
#pragma unroll
    for (int a = 0; a < 2; ++a)
#pragma unroll
        for (int m = 0; m < 4; ++m) pacc[a][m] = (f4_t){0.f, 0.f, 0.f, 0.f};

    for (int hp = 0; hp < 4; ++hp) {
        // (a) gather: q,k row-major; v transposed
        {
            const int i = tid >> 3, dg = tid & 7;
            const int t = p - 63 + i;
            const u16* src = (t >= 0) ? (qkvtb + (size_t)((bb << 10) + t) * 768) : qb0c;
#pragma unroll
            for (int hh = 0; hh < 2; ++hh) {
                const u16* s2 = src + (hp * 2 + hh) * HD_ + dg * 4;
                *(uint2*)(sm.u.att.qbop + hh * 2560 + i * 40 + dg * 4) = *(const uint2*)(s2);
                *(uint2*)(sm.u.att.kbpb + hh * 2560 + i * 40 + dg * 4) = *(const uint2*)(s2 + EE_);
                U4 v4; v4.u = *(const uint2*)(s2 + 2 * EE_);
#pragma unroll
                for (int c = 0; c < 4; ++c)
                    sm.u.att.vtb[hh * 2304 + (dg * 4 + c) * 72 + i] = v4.h[c];
            }
        }
        __syncthreads();
        const int hh = wv >> 2, mt_ = wv & 3;
        // (b) scores MFMA + in-register softmax
        const bf8_t aq = *(const bf8_t*)(sm.u.att.qbop + hh * 2560 + (mt_ * 16 + col) * 40 + quad * 8);
        f4_t sc[4];
#pragma unroll
        for (int nt = 0; nt < 4; ++nt) {
            const bf8_t bk = *(const bf8_t*)(sm.u.att.kbpb + hh * 2560 + (nt * 16 + col) * 40 + quad * 8);
            f4_t z = {0.f, 0.f, 0.f, 0.f};
            sc[nt] = MFMA_B16(aq, bk, z);
        }
#pragma unroll
        for (int j = 0; j < 4; ++j) {
            float s0 = sc[0][j] * SCALE_, s1 = sc[1][j] * SCALE_;
            float s2v = sc[2][j] * SCALE_, s3 = sc[3][j] * SCALE_;
            float m = fmaxf(fmaxf(s0, s1), fmaxf(s2v, s3));
            m = fmaxf(m, __shfl_xor(m, 1)); m = fmaxf(m, __shfl_xor(m, 2));
            m = fmaxf(m, __shfl_xor(m, 4)); m = fmaxf(m, __shfl_xor(m, 8));
            const float e0 = __expf(s0 - m), e1 = __expf(s1 - m);
            const float e2 = __expf(s2v - m), e3 = __expf(s3 - m);
            float s = e0 + e1 + e2 + e3;
            s += __shfl_xor(s, 1); s += __shfl_xor(s, 2);
            s += __shfl_xor(s, 4); s += __shfl_xor(s, 8);
            const float inv = 1.f / s;
            sc[0][j] = e0 * inv; sc[1][j] = e1 * inv;
            sc[2][j] = e2 * inv; sc[3][j] = e3 * inv;
        }
        __syncthreads();   // all q/k reads done; pb may overwrite kb, opair->qb
        // write P (aliases kb region)
        u16* pbh = sm.u.att.kbpb + hh * 4608;
        const int r0 = mt_ * 16 + quad * 4;
#pragma unroll
        for (int nt = 0; nt < 4; ++nt)
#pragma unroll
            for (int j = 0; j < 4; ++j)
                pbh[(r0 + j) * 72 + nt * 16 + col] = bf16r(sc[nt][j]);
        // PV (same-wave P rows; vtb stable)
        f4_t ov[2];
        ov[0] = (f4_t){0.f, 0.f, 0.f, 0.f}; ov[1] = (f4_t){0.f, 0.f, 0.f, 0.f};
#pragma unroll
        for (int ks = 0; ks < 2; ++ks) {
            const bf8_t ap = *(const bf8_t*)(pbh + (mt_ * 16 + col) * 72 + ks * 32 + quad * 8);
#pragma unroll
            for (int ntl = 0; ntl < 2; ++ntl) {
                const bf8_t bv = *(const bf8_t*)(sm.u.att.vtb + hh * 2304 +
                                                 (ntl * 16 + col) * 72 + ks * 32 + quad * 8);
                ov[ntl] = MFMA_B16(ap, bv, ov[ntl]);
            }
        }
        // opair (aliases qb region)
#pragma unroll
        for (int ntl = 0; ntl < 2; ++ntl)
#pragma unroll
            for (int j = 0; j < 4; ++j)
                sm.u.att.qbop[(r0 + j) * 72 + hh * 32 + ntl * 16 + col] = bf16r(ov[ntl][j]);
        __syncthreads();
        // (c) proj accumulate
#pragma unroll
        for (int ks = 0; ks < 2; ++ks) {
            bf8_t ao[4];
#pragma unroll
            for (int mt = 0; mt < 4; ++mt)
                ao[mt] = *(const bf8_t*)(sm.u.att.qbop + (mt * 16 + col) * 72 + ks * 32 + quad * 8);
#pragma unroll
            for (int ntl = 0; ntl < 2; ++ntl) {
                const bf8_t bw = *(const bf8_t*)(wob + ((wv * 2 + ntl) * 16 + col) * EE_ +
                                                 hp * 64 + ks * 32 + quad * 8);
#pragma unroll
                for (int mt = 0; mt < 4; ++mt) pacc[ntl][mt] = MFMA_B16(ao[mt], bw, pacc[ntl][mt]);
            }
        }
        __syncthreads();
    }

    // ---- combine x0 + attn + bias into registers, then LN1 -> xb
    float x[2][4][4];
#pragma unroll
    for (int mt = 0; mt < 4; ++mt)
#pragma unroll
        for (int j = 0; j < 4; ++j) {
            const int row = mt * 16 + quad * 4 + j;
            const int t = p - 63 + row;
            const size_t base = (size_t)((bb << 10) + t) * EE_;
            const float e0 = (t >= 0) ? emb[base + colg0] : 0.f;
            const float e1 = (t >= 0) ? emb[base + colg1] : 0.f;
            x[0][mt][j] = e0 + aob_0 + pacc[0][mt][j];
            x[1][mt][j] = e1 + aob_1 + pacc[1][mt][j];
        }
    reg_ln(x, sm, g1_0, g1_1, b1_0, b1_1, tid, wv, col, quad, colg0, colg1);
    __syncthreads();

    // ---- FFN (MFMA, f-chunked 4 x 256)
    f4_t facc[2][4];
#pragma unroll
    for (int a = 0; a < 2; ++a)
#pragma unroll
        for (int m = 0; m < 4; ++m) facc[a][m] = (f4_t){0.f, 0.f, 0.f, 0.f};

    for (int c = 0; c < 4; ++c) {
        {
            f4_t hacc[2][4];
#pragma unroll
            for (int a = 0; a < 2; ++a)
#pragma unroll
                for (int m = 0; m < 4; ++m) hacc[a][m] = (f4_t){0.f, 0.f, 0.f, 0.f};
#pragma unroll 2
            for (int ks = 0; ks < 8; ++ks) {
                bf8_t axr[4];
#pragma unroll
                for (int mt = 0; mt < 4; ++mt)
                    axr[mt] = *(const bf8_t*)(sm.xb + (mt * 16 + col) * XBP + ks * 32 + quad * 8);
#pragma unroll
                for (int ntl = 0; ntl < 2; ++ntl) {
                    const int f = (c * 16 + wv * 2 + ntl) * 16 + col;
                    const bf8_t bw = *(const bf8_t*)(w1b + f * EE_ + ks * 32 + quad * 8);
#pragma unroll
                    for (int mt = 0; mt < 4; ++mt) hacc[ntl][mt] = MFMA_B16(axr[mt], bw, hacc[ntl][mt]);
                }
            }
#pragma unroll
            for (int ntl = 0; ntl < 2; ++ntl) {
                const int f = (c * 16 + wv * 2 + ntl) * 16 + col;
                const float bv = f1b[f];
                const int lc = (wv * 2 + ntl) * 16 + col;
#pragma unroll
                for (int mt = 0; mt < 4; ++mt)
#pragma unroll
                    for (int j = 0; j < 4; ++j)
                        sm.u.ffn.hb[(mt * 16 + quad * 4 + j) * XBP + lc] =
                            bf16r(silu_f(hacc[ntl][mt][j] + bv));
            }
        }
        __syncthreads();
        {
#pragma unroll 2
            for (int ks = 0; ks < 8; ++ks) {
                bf8_t ah[4];
#pragma unroll
                for (int mt = 0; mt < 4; ++mt)
                    ah[mt] = *(const bf8_t*)(sm.u.ffn.hb + (mt * 16 + col) * XBP + ks * 32 + quad * 8);
#pragma unroll
                for (int ntl = 0; ntl < 2; ++ntl) {
                    const int e = (wv * 2 + ntl) * 16 + col;
                    const bf8_t bw = *(const bf8_t*)(w2b + e * FF_ + c * 256 + ks * 32 + quad * 8);
#pragma unroll
                    for (int mt = 0; mt < 4; ++mt) facc[ntl][mt] = MFMA_B16(ah[mt], bw, facc[ntl][mt]);
                }
            }
        }
        __syncthreads();
    }
    // reconstruct x from bf16 xb, add FFN2 + bias, LN2 -> x1
#pragma unroll
    for (int mt = 0; mt < 4; ++mt)
#pragma unroll
        for (int j = 0; j < 4; ++j) {
            const int row = mt * 16 + quad * 4 + j;
            x[0][mt][j] = b2f(sm.xb[row * XBP + colg0]) + facc[0][mt][j] + f2b_0;
            x[1][mt][j] = b2f(sm.xb[row * XBP + colg1]) + facc[1][mt][j] + f2b_1;
        }
    __syncthreads();   // xb reads done before reg_ln overwrites
    reg_ln(x, sm, g2_0, g2_1, b2_0, b2_1, tid, wv, col, quad, colg0, colg1);
    if (quad == 3) {   // row 63 = mt3,quad3,j3 holders
        sm.x1row[colg0] = x[0][3][3];
        sm.x1row[colg1] = x[1][3][3];
    }
    __syncthreads();

    // =================== Layer 1 (last-token path) ===================
    for (int hp = 0; hp < 4; ++hp) {
        {
            const int hf = wv >> 2, mtk = wv & 3;
            f4_t kacc[4];
#pragma unroll
            for (int a = 0; a < 4; ++a) kacc[a] = (f4_t){0.f, 0.f, 0.f, 0.f};
#pragma unroll 2
            for (int ks = 0; ks < 8; ++ks) {
                const bf8_t ax = *(const bf8_t*)(sm.xb + (mtk * 16 + col) * XBP + ks * 32 + quad * 8);
#pragma unroll
                for (int nt = 0; nt < 4; ++nt) {
                    const int wr = hf * EE_ + hp * 64 + nt * 16 + col;
                    const bf8_t bw = *(const bf8_t*)(wkvb + wr * EE_ + ks * 32 + quad * 8);
                    kacc[nt] = MFMA_B16(ax, bw, kacc[nt]);
                }
            }
            float* dst = hf ? sm.u.tail.v1p : sm.u.tail.k1p;
#pragma unroll
            for (int nt = 0; nt < 4; ++nt) {
                const int cc = nt * 16 + col;
                const float bs = qkv_b1[(hf + 1) * EE_ + hp * 64 + cc];
#pragma unroll
                for (int j = 0; j < 4; ++j)
                    dst[(mtk * 16 + quad * 4 + j) * 68 + cc] = kacc[nt][j] + bs;
            }
        }
        if (tid < 64) {   // q1 for token 63 (bf16-weight dot)
            const u16* wq = wq1b + (hp * 64 + tid) * EE_;
            float s = 0.f;
#pragma unroll 8
            for (int k2 = 0; k2 < 128; ++k2) {
                const u32 u = *(const u32*)(wq + k2 * 2);
                s += sm.x1row[2 * k2] * b2f_lo(u) + sm.x1row[2 * k2 + 1] * b2f_hi(u);
            }
            sm.q1b[tid] = s + qkv_b1[hp * 64 + tid];
        }
        __syncthreads();
        if (tid < 128) {   // scores + softmax (2 heads, 2 waves)
            const int hh = tid >> 6, jj = tid & 63;
            const float* kr = sm.u.tail.k1p + jj * 68 + hh * 32;
            const float* qv = sm.q1b + hh * 32;
            float s = 0.f;
#pragma unroll
            for (int d = 0; d < 32; ++d) s += qv[d] * kr[d];
            s *= SCALE_;
            const float m = wmax(s);
            const float e = __expf(s - m);
            const float su = wsum(e);
            sm.sbuf2[tid] = e / su;
        }
        __syncthreads();
        if (tid < 64) {   // o1 slices
            const int hh = tid >> 5, d = tid & 31;
            float acc = 0.f;
            for (int j = 0; j < 64; ++j)
                acc += sm.sbuf2[hh * 64 + j] * sm.u.tail.v1p[j * 68 + hh * 32 + d];
            sm.o1b[hp * 64 + hh * 32 + d] = acc;
        }
        __syncthreads();
    }

    // x2 = x1[63] + o1 @ Wo1^T + b  -> global (pre-LN; tail kernel finishes)
    if (tid < 256) {
        const u16* wr = wob1 + tid * EE_;
        float s = 0.f;
#pragma unroll 8
        for (int k2 = 0; k2 < 128; ++k2) {
            const u32 u = *(const u32*)(wr + k2 * 2);
            s += sm.o1b[2 * k2] * b2f_lo(u) + sm.o1b[2 * k2 + 1] * b2f_hi(u);
        }
        x2g[n * EE_ + tid] = sm.x1row[tid] + s + aob1p[tid];
    }
}

// ---------------------------------------------------------------------------
// Tail kernel: batched LN1'->FFN1'->FFN2'->LN2'->head for token 63 of all
// windows. grid = 512 blocks x 4 windows, block = 256.
// ---------------------------------------------------------------------------
__global__ __launch_bounds__(256) void k_tail(
    const float* __restrict__ x2g, const u16* __restrict__ w1b1,
    const float* __restrict__ f1b1, const u16* __restrict__ w2b1,
    const float* __restrict__ f2b1, const float* __restrict__ g1,
    const float* __restrict__ b1, const float* __restrict__ g2,
    const float* __restrict__ b2, const float* __restrict__ hw,
    const float* __restrict__ hbb, float* __restrict__ out) {
    __shared__ float xa[4 * 260];
    __shared__ float hid[4 * 1024];
    const int tid = threadIdx.x, lane = tid & 63, w = tid >> 6;
    const int n0 = blockIdx.x * 4;
    // LN1': one wave per window
    {
        const float* src = x2g + (size_t)(n0 + w) * EE_;
        const float v0 = src[lane], v1 = src[lane + 64], v2 = src[lane + 128], v3 = src[lane + 192];
        const float m = wsum(v0 + v1 + v2 + v3) * 0.00390625f;
        const float d0 = v0 - m, d1 = v1 - m, d2 = v2 - m, d3 = v3 - m;
        const float var = wsum(d0 * d0 + d1 * d1 + d2 * d2 + d3 * d3) * 0.00390625f;
        const float rs = rsqrtf(var + 1e-5f);
        xa[w * 260 + lane] = d0 * rs * g1[lane] + b1[lane];
        xa[w * 260 + lane + 64] = d1 * rs * g1[lane + 64] + b1[lane + 64];
        xa[w * 260 + lane + 128] = d2 * rs * g1[lane + 128] + b1[lane + 128];
        xa[w * 260 + lane + 192] = d3 * rs * g1[lane + 192] + b1[lane + 192];
    }
    __syncthreads();
    // FFN1: each thread 4 f-rows x 4 windows
#pragma unroll 1
    for (int r = 0; r < 4; ++r) {
        const int f = r * 256 + tid;
        const u16* wrow = w1b1 + f * EE_;
        float a0 = 0.f, a1 = 0.f, a2 = 0.f, a3 = 0.f;
#pragma unroll 4
        for (int k2 = 0; k2 < 128; ++k2) {
            const u32 u = *(const u32*)(wrow + k2 * 2);
            const float lo = b2f_lo(u), hi = b2f_hi(u);
            const float2 h0 = *(const float2*)(xa + 0 * 260 + k2 * 2);
            const float2 h1 = *(const float2*)(xa + 1 * 260 + k2 * 2);
            const float2 h2 = *(const float2*)(xa + 2 * 260 + k2 * 2);
            const float2 h3 = *(const float2*)(xa + 3 * 260 + k2 * 2);
            a0 += h0.x * lo + h0.y * hi;
            a1 += h1.x * lo + h1.y * hi;
            a2 += h2.x * lo + h2.y * hi;
            a3 += h3.x * lo + h3.y * hi;
        }
        const float bv = f1b1[f];
        hid[0 * 1024 + f] = silu_f(a0 + bv);
        hid[1 * 1024 + f] = silu_f(a1 + bv);
        hid[2 * 1024 + f] = silu_f(a2 + bv);
        hid[3 * 1024 + f] = silu_f(a3 + bv);
    }
    __syncthreads();
    // FFN2: thread e = tid
    {
        const u16* wrow = w2b1 + tid * FF_;
        float a0 = 0.f, a1 = 0.f, a2 = 0.f, a3 = 0.f;
#pragma unroll 4
        for (int k2 = 0; k2 < 512; ++k2) {
            const u32 u = *(const u32*)(wrow + k2 * 2);
            const float lo = b2f_lo(u), hi = b2f_hi(u);
            const float2 h0 = *(const float2*)(hid + 0 * 1024 + k2 * 2);
            const float2 h1 = *(const float2*)(hid + 1 * 1024 + k2 * 2);
            const float2 h2 = *(const float2*)(hid + 2 * 1024 + k2 * 2);
            const float2 h3 = *(const float2*)(hid + 3 * 1024 + k2 * 2);
            a0 += h0.x * lo + h0.y * hi;
            a1 += h1.x * lo + h1.y * hi;
            a2 += h2.x * lo + h2.y * hi;
            a3 += h3.x * lo + h3.y * hi;
        }
        const float bv = f2b1[tid];
        const float r0 = xa[0 * 260 + tid] + a0 + bv;
        const float r1 = xa[1 * 260 + tid] + a1 + bv;
        const float r2 = xa[2 * 260 + tid] + a2 + bv;
        const float r3 = xa[3 * 260 + tid] + a3 + bv;
        __syncthreads();
        xa[0 * 260 + tid] = r0;
        xa[1 * 260 + tid] = r1;
        xa[2 * 260 + tid] = r2;
        xa[3 * 260 + tid] = r3;
    }
    __syncthreads();
    // LN2'
    {
        float* row = xa + w * 260;
        const float v0 = row[lane], v1 = row[lane + 64], v2 = row[lane + 128], v3 = row[lane + 192];
        const float m = wsum(v0 + v1 + v2 + v3) * 0.00390625f;
        const float d0 = v0 - m, d1 = v1 - m, d2 = v2 - m, d3 = v3 - m;
        const float var = wsum(d0 * d0 + d1 * d1 + d2 * d2 + d3 * d3) * 0.00390625f;
        const float rs = rsqrtf(var + 1e-5f);
        __syncthreads();
        row[lane] = d0 * rs * g2[lane] + b2[lane];
        row[lane + 64] = d1 * rs * g2[lane + 64] + b2[lane + 64];
        row[lane + 128] = d2 * rs * g2[lane + 128] + b2[lane + 128];
        row[lane + 192] = d3 * rs * g2[lane + 192] + b2[lane + 192];
    }
    __syncthreads();
    // head
    if (tid < 4 * OUT_) {
        const int win = tid / OUT_, o = tid % OUT_;
        const float* wr = hw + o * EE_;
        const float* xr = xa + win * 260;
        float s = 0.f;
#pragma unroll 8
        for (int c4 = 0; c4 < 64; ++c4)
            s += dot4(*(const float4*)(xr + c4 * 4), *(const float4*)(wr + c4 * 4));
        out[(n0 + win) * OUT_ + o] = s + hbb[o];
    }
}

// ---------------------------------------------------------------------------
extern "C" void kernel_launch(void* const* d_in, const int* in_sizes, int n_in,
                              void* d_out, int out_size, void* d_ws, size_t ws_size,
                              hipStream_t stream) {
    (void)in_sizes; (void)n_in; (void)out_size; (void)ws_size;
    const float* inputs = (const float*)d_in[0];
    const float* embed_w = (const float*)d_in[1];
    const float* embed_b = (const float*)d_in[2];
    const float* qkv_w = (const float*)d_in[3];
    const float* qkv_b = (const float*)d_in[4];
    const float* attn_out_w = (const float*)d_in[5];
    const float* attn_out_b = (const float*)d_in[6];
    const float* ln1_g = (const float*)d_in[7];
    const float* ln1_b = (const float*)d_in[8];
    const float* ffn1_w = (const float*)d_in[9];
    const float* ffn1_b = (const float*)d_in[10];
    const float* ffn2_w = (const float*)d_in[11];
    const float* ffn2_b = (const float*)d_in[12];
    const float* ln2_g = (const float*)d_in[13];
    const float* ln2_b = (const float*)d_in[14];
    const float* head_w = (const float*)d_in[15];
    const float* head_b = (const float*)d_in[16];
    float* out = (float*)d_out;

    char* wsb = (char*)d_ws;
    size_t off = 0;
    auto alloc = [&](size_t bytes) { char* p = wsb + off; off += (bytes + 511) & ~511ull; return p; };
    float* emb   = (float*)alloc((size_t)NWIN * EE_ * 4);        // 2 MB
    u16*   qkvtb = (u16*)alloc((size_t)NWIN * 768 * 2);          // 3 MB
    float* x2g   = (float*)alloc((size_t)NWIN * EE_ * 4);        // 2 MB
    u16*   w1b   = (u16*)alloc(FF_ * EE_ * 2);
    u16*   w2b   = (u16*)alloc(EE_ * FF_ * 2);
    u16*   wob   = (u16*)alloc(EE_ * EE_ * 2);
    u16*   wkvb  = (u16*)alloc(2 * EE_ * EE_ * 2);
    u16*   qb0c  = (u16*)alloc(3 * EE_ * 2);
    u16*   w1b1  = (u16*)alloc(FF_ * EE_ * 2);
    u16*   w2b1  = (u16*)alloc(EE_ * FF_ * 2);
    u16*   wob1  = (u16*)alloc(EE_ * EE_ * 2);
    u16*   wq1b  = (u16*)alloc(EE_ * EE_ * 2);
    u16*   wq0b  = (u16*)alloc(3 * EE_ * EE_ * 2);

    CvtArgs ca;
    ca.s[0] = ffn1_w;                    ca.d[0] = w1b;  ca.n[0] = FF_ * EE_;
    ca.s[1] = ffn2_w;                    ca.d[1] = w2b;  ca.n[1] = EE_ * FF_;
    ca.s[2] = attn_out_w;                ca.d[2] = wob;  ca.n[2] = EE_ * EE_;
    ca.s[3] = qkv_w + 3 * EE_ * EE_ + EE_ * EE_; ca.d[3] = wkvb; ca.n[3] = 2 * EE_ * EE_;
    ca.s[4] = qkv_b;                     ca.d[4] = qb0c; ca.n[4] = 3 * EE_;
    ca.s[5] = ffn1_w + FF_ * EE_;        ca.d[5] = w1b1; ca.n[5] = FF_ * EE_;
    ca.s[6] = ffn2_w + EE_ * FF_;        ca.d[6] = w2b1; ca.n[6] = EE_ * FF_;
    ca.s[7] = attn_out_w + EE_ * EE_;    ca.d[7] = wob1; ca.n[7] = EE_ * EE_;
    ca.s[8] = qkv_w + 3 * EE_ * EE_;     ca.d[8] = wq1b; ca.n[8] = EE_ * EE_;
    ca.s[9] = qkv_w;                     ca.d[9] = wq0b; ca.n[9] = 3 * EE_ * EE_;

    k_cvt_all<<<768, 256, 0, stream>>>(ca);
    k_embed<<<NWIN, 256, 0, stream>>>(inputs, embed_w, embed_b, emb);
    k_qkv0m<<<NWIN / 16, 512, 0, stream>>>(emb, wq0b, qkv_b, qkvtb);
    k_fused<<<NWIN, NT, 0, stream>>>(emb, qkvtb, qb0c, w1b, w2b, wob, wkvb,
                                     wq1b, wob1, qkv_b, attn_out_b,
                                     ln1_g, ln1_b, ffn1_b, ffn2_b,
                                     ln2_g, ln2_b, x2g);
    k_tail<<<NWIN / 4, 256, 0, stream>>>(x2g, w1b1, ffn1_b + FF_, w2b1, ffn2_b + EE_,
                                         ln1_g + EE_, ln1_b + EE_, ln2_g + EE_, ln2_b + EE_,
                                         head_w, head_b, out);
}